// Round 1
// baseline (982.837 us; speedup 1.0000x reference)
//
#include <hip/hip_runtime.h>

// MultiHeadSelfAttn decode: q (1,32,512) fp32, k/v (8192,32,512) fp32.
// out (1,32,512) fp32. N_HEAD=8, D_HEAD=64, SCALE=1/8, CLIP=10.
// score = 10*tanh(SCALE * q.k)  -> bounded to [-10,10] -> exp() safe in fp32
// -> single-pass softmax (no running max), split-K with tiny reduce kernel.

#define N_PAIR    256        // 32 batch * 8 heads
#define DH        64         // head dim
#define KLEN      8192
#define SPLITS    8          // klen split factor: 2048 blocks total
#define ROWSTRIDE 16384      // floats per j row (32*512)
#define SCALE_F   0.125f
#define CLIP_F    10.0f

// Lane layout per wave: dd = lane&15 covers d (float4 each), jj = lane>>4
// covers 4 consecutive j rows. 16-lane group reads one contiguous 256 B chunk.
__global__ __launch_bounds__(256) void attn_partial(
    const float* __restrict__ q, const float* __restrict__ k,
    const float* __restrict__ v, float* __restrict__ part_num,
    float* __restrict__ part_den)
{
    const int p    = blockIdx.x & (N_PAIR - 1);   // pair = b*8+n
    const int s    = blockIdx.x >> 8;             // split index
    const int tid  = threadIdx.x;
    const int lane = tid & 63;
    const int w    = tid >> 6;                    // wave 0..3
    const int dd   = lane & 15;                   // float4 slot in d
    const int jj   = lane >> 4;                   // 0..3

    const int base = p * DH;                      // chunk offset within a row
    const float4 qv = *(const float4*)(q + base + dd * 4);

    float4 acc = make_float4(0.f, 0.f, 0.f, 0.f);
    float  den = 0.f;

    const int jbase = s * (KLEN / SPLITS);
    const int niter = (KLEN / SPLITS) / 16;       // 16 rows per block-iter

    #pragma unroll 4
    for (int it = 0; it < niter; ++it) {
        const int j = jbase + it * 16 + w * 4 + jj;
        const size_t off = (size_t)j * ROWSTRIDE + base + dd * 4;
        const float4 kv = *(const float4*)(k + off);
        const float4 vv = *(const float4*)(v + off);

        float pd = kv.x * qv.x + kv.y * qv.y + kv.z * qv.z + kv.w * qv.w;
        // butterfly sum across the 16 dd-lanes (masks 1,2,4,8 stay in-group)
        pd += __shfl_xor(pd, 1);
        pd += __shfl_xor(pd, 2);
        pd += __shfl_xor(pd, 4);
        pd += __shfl_xor(pd, 8);

        const float x  = pd * SCALE_F;
        const float e2 = __expf(2.f * x);
        const float th = 1.f - 2.f / (e2 + 1.f);   // tanh, inf-safe form
        const float wg = __expf(CLIP_F * th);      // score in [-10,10]

        acc.x += wg * vv.x;
        acc.y += wg * vv.y;
        acc.z += wg * vv.z;
        acc.w += wg * vv.w;
        den   += wg;
    }

    // reduce across the 4 jj groups (masks 16,32 flip only jj bits)
    acc.x += __shfl_xor(acc.x, 16); acc.x += __shfl_xor(acc.x, 32);
    acc.y += __shfl_xor(acc.y, 16); acc.y += __shfl_xor(acc.y, 32);
    acc.z += __shfl_xor(acc.z, 16); acc.z += __shfl_xor(acc.z, 32);
    acc.w += __shfl_xor(acc.w, 16); acc.w += __shfl_xor(acc.w, 32);
    den   += __shfl_xor(den, 16);   den   += __shfl_xor(den, 32);

    // cross-wave reduction in LDS
    __shared__ float lacc[4][DH];
    __shared__ float lden[4];
    if (lane < 16) {
        lacc[w][dd * 4 + 0] = acc.x;
        lacc[w][dd * 4 + 1] = acc.y;
        lacc[w][dd * 4 + 2] = acc.z;
        lacc[w][dd * 4 + 3] = acc.w;
        if (lane == 0) lden[w] = den;
    }
    __syncthreads();
    if (tid < DH) {
        const float num = lacc[0][tid] + lacc[1][tid] + lacc[2][tid] + lacc[3][tid];
        const float dn  = lden[0] + lden[1] + lden[2] + lden[3];
        part_num[(size_t)blockIdx.x * DH + tid] = num;
        if (tid == 0) part_den[blockIdx.x] = dn;
    }
}

__global__ __launch_bounds__(64) void attn_reduce(
    const float* __restrict__ part_num, const float* __restrict__ part_den,
    float* __restrict__ out)
{
    const int p = blockIdx.x;     // 0..255
    const int d = threadIdx.x;    // 0..63
    float num = 0.f, den = 0.f;
    #pragma unroll
    for (int s = 0; s < SPLITS; ++s) {
        const int slot = s * N_PAIR + p;
        num += part_num[(size_t)slot * DH + d];
        den += part_den[slot];
    }
    out[p * DH + d] = num / den;  // out offset b*512+n*64+d == p*64+d
}

extern "C" void kernel_launch(void* const* d_in, const int* in_sizes, int n_in,
                              void* d_out, int out_size, void* d_ws, size_t ws_size,
                              hipStream_t stream)
{
    const float* q = (const float*)d_in[0];
    const float* k = (const float*)d_in[1];
    const float* v = (const float*)d_in[2];
    float* out = (float*)d_out;

    float* part_num = (float*)d_ws;                               // 2048*64 fp32
    float* part_den = part_num + (size_t)SPLITS * N_PAIR * DH;    // 2048 fp32

    attn_partial<<<dim3(SPLITS * N_PAIR), dim3(256), 0, stream>>>(
        q, k, v, part_num, part_den);
    attn_reduce<<<dim3(N_PAIR), dim3(64), 0, stream>>>(part_num, part_den, out);
}